// Round 1
// baseline (94.043 us; speedup 1.0000x reference)
//
#include <hip/hip_runtime.h>

// Problem constants from reference setup_inputs(): B=256, D=512, fp32.
#define BB 256
#define DD 512
#define NCHUNK 32                      // row chunks in phase 1 (was 8)
#define ROWS_PER_CHUNK (BB / NCHUNK)   // 8

// Structure history (journal):
//  R1 (two tiny launches, NCHUNK=8): 60.4 us  -- best so far
//  R2 (1-block fused): +9.4 us -- 1-CU serialization of the transcendentals
//  R3 (1-launch ticket/fence): +3.3 us -- device fence > kernel->kernel gap
//  R4 (this): keep two launches; widen phase1 8->32 CUs and batch all loads
//  before compute (one memory round-trip per chunk instead of a 4-deep
//  pipelined loop). Phase2 combines 32 chunks instead of 8 (320 KB, L2-hot).
//
// Math: per-d over all rows:  A = sum(exp(lv) + mu^2), P = sum(exp(-lv)),
//       M = sum(mu), Q = sum(mu*exp(-lv)), R = sum(mu^2*exp(-lv))
// Full = sum_d (A*P - 2*M*Q + B*R);  answer = (Full - D*B^2) / (2B)
// ws layout: ws[chunk][stat(5)][DD] floats -> 32*5*512*4 = 320 KB

__global__ __launch_bounds__(DD) void udl_phase1(const float* __restrict__ mu,
                                                 const float* __restrict__ lv,
                                                 float* __restrict__ ws) {
    const int d = threadIdx.x;        // 0..511 (coalesced across the row)
    const int chunk = blockIdx.x;     // 0..31
    const int row0 = chunk * ROWS_PER_CHUNK;

    // Batch ALL loads first: 16 independent global loads in flight at once,
    // so the chunk costs ~one HBM/L3 round-trip instead of unroll-4 waves.
    float m[ROWS_PER_CHUNK], l[ROWS_PER_CHUNK];
#pragma unroll
    for (int r = 0; r < ROWS_PER_CHUNK; ++r) {
        const int idx = (row0 + r) * DD + d;   // contiguous across threads
        m[r] = mu[idx];
        l[r] = lv[idx];
    }

    float A = 0.f, P = 0.f, M = 0.f, Q = 0.f, R = 0.f;
#pragma unroll
    for (int r = 0; r < ROWS_PER_CHUNK; ++r) {
        const float ev = __expf(l[r]);
        const float iv = __expf(-l[r]);
        A += ev + m[r] * m[r];
        P += iv;
        M += m[r];
        const float miv = m[r] * iv;
        Q += miv;
        R += m[r] * miv;
    }

    float* o = ws + (size_t)chunk * 5 * DD;
    o[0 * DD + d] = A;
    o[1 * DD + d] = P;
    o[2 * DD + d] = M;
    o[3 * DD + d] = Q;
    o[4 * DD + d] = R;
}

// Phase 2: combine chunk partials per d, form c[d] = A*P - 2*M*Q + B*R,
// block-reduce over d (double), apply closed form, write scalar.
__global__ __launch_bounds__(DD) void udl_phase2(const float* __restrict__ ws,
                                                 float* __restrict__ out) {
    const int d = threadIdx.x;        // 512 threads, one per column
    float A = 0.f, P = 0.f, M = 0.f, Q = 0.f, R = 0.f;
#pragma unroll
    for (int c = 0; c < NCHUNK; ++c) {
        const float* o = ws + (size_t)c * 5 * DD;
        A += o[0 * DD + d];
        P += o[1 * DD + d];
        M += o[2 * DD + d];
        Q += o[3 * DD + d];
        R += o[4 * DD + d];
    }
    double cd = (double)A * (double)P
              - 2.0 * (double)M * (double)Q
              + (double)BB * (double)R;

    // wave (64-lane) shuffle reduce, then LDS across the 8 waves
    for (int off = 32; off > 0; off >>= 1)
        cd += __shfl_down(cd, off, 64);

    __shared__ double sred[DD / 64];
    const int wid = threadIdx.x >> 6;
    const int lane = threadIdx.x & 63;
    if (lane == 0) sred[wid] = cd;
    __syncthreads();

    if (threadIdx.x == 0) {
        double full = 0.0;
#pragma unroll
        for (int w = 0; w < DD / 64; ++w) full += sred[w];
        const double result = (full - (double)DD * (double)BB * (double)BB)
                              / (2.0 * (double)BB);
        out[0] = (float)result;
    }
}

extern "C" void kernel_launch(void* const* d_in, const int* in_sizes, int n_in,
                              void* d_out, int out_size, void* d_ws, size_t ws_size,
                              hipStream_t stream) {
    const float* mu = (const float*)d_in[0];
    const float* lv = (const float*)d_in[1];
    float* out = (float*)d_out;
    float* ws = (float*)d_ws;

    udl_phase1<<<NCHUNK, DD, 0, stream>>>(mu, lv, ws);
    udl_phase2<<<1, DD, 0, stream>>>(ws, out);
}

// Round 3
// 59.677 us; speedup vs baseline: 1.5759x; 1.5759x over previous
//
#include <hip/hip_runtime.h>

// Problem constants from reference setup_inputs(): B=256, D=512, fp32.
#define BB 256
#define DD 512
#define NCHUNK 8                       // row chunks in phase 1
#define ROWS_PER_CHUNK (BB / NCHUNK)   // 32

// Structure history (journal):
//  R1 (two tiny launches, NCHUNK=8, serial loops): 60.4 us
//  R2 (1-block fused): +9.4 us -- 1-CU serialization of transcendentals
//  R3 (1-launch ticket/fence): +3.3 us -- device fence > kernel->kernel gap
//  R4 (NCHUNK=32): 94.0 us FAILED -- phase2 became 160 serialized scalar
//     loads/thread (VGPR=12, VALUBusy 0.009%, 42.9 us idle-latency).
//     Lesson: phase2 per-thread memory ILP is the lever, not phase1 width.
//  R5: NCHUNK=8 + register-batched loads in both phases. Bench infra failed
//     twice (no GPU result) -- R6 is an exact resubmit of R5.
//
// Math: per-d over all rows:  A = sum(exp(lv) + mu^2), P = sum(exp(-lv)),
//       M = sum(mu), Q = sum(mu*exp(-lv)), R = sum(mu^2*exp(-lv))
// Full = sum_d (A*P - 2*M*Q + B*R);  answer = (Full - D*B^2) / (2B)
// ws layout: ws[chunk][stat(5)][DD] floats -> 8*5*512*4 = 80 KB

__global__ __launch_bounds__(DD) void udl_phase1(const float* __restrict__ mu,
                                                 const float* __restrict__ lv,
                                                 float* __restrict__ ws) {
    const int d = threadIdx.x;        // 0..511 (coalesced across the row)
    const int chunk = blockIdx.x;     // 0..7
    const int row0 = chunk * ROWS_PER_CHUNK;

    // Batch ALL 64 loads first (fully unrolled, static indices -> registers):
    // every load is independent and in flight before the first exp.
    float m[ROWS_PER_CHUNK], l[ROWS_PER_CHUNK];
#pragma unroll
    for (int r = 0; r < ROWS_PER_CHUNK; ++r) {
        const int idx = (row0 + r) * DD + d;   // contiguous across threads
        m[r] = mu[idx];
        l[r] = lv[idx];
    }

    float A = 0.f, P = 0.f, M = 0.f, Q = 0.f, R = 0.f;
#pragma unroll
    for (int r = 0; r < ROWS_PER_CHUNK; ++r) {
        const float ev = __expf(l[r]);
        const float iv = __expf(-l[r]);
        A += ev + m[r] * m[r];
        P += iv;
        M += m[r];
        const float miv = m[r] * iv;
        Q += miv;
        R += m[r] * miv;
    }

    float* o = ws + (size_t)chunk * 5 * DD;
    o[0 * DD + d] = A;
    o[1 * DD + d] = P;
    o[2 * DD + d] = M;
    o[3 * DD + d] = Q;
    o[4 * DD + d] = R;
}

// Phase 2: combine chunk partials per d, form c[d] = A*P - 2*M*Q + B*R,
// block-reduce over d (double), apply closed form, write scalar.
__global__ __launch_bounds__(DD) void udl_phase2(const float* __restrict__ ws,
                                                 float* __restrict__ out) {
    const int d = threadIdx.x;        // 512 threads, one per column

    // Batch ALL 40 loads (8 chunks x 5 stats) into registers before any
    // arithmetic. Fully unrolled, static indices -> VGPRs, ~40 outstanding
    // loads -> single cold-memory round trip (R4's 42.9us was this chain
    // serialized at VGPR=12).
    float v[NCHUNK][5];
#pragma unroll
    for (int c = 0; c < NCHUNK; ++c) {
        const float* o = ws + (size_t)c * 5 * DD + d;
#pragma unroll
        for (int s = 0; s < 5; ++s)
            v[c][s] = o[s * DD];
    }

    float A = 0.f, P = 0.f, M = 0.f, Q = 0.f, R = 0.f;
#pragma unroll
    for (int c = 0; c < NCHUNK; ++c) {
        A += v[c][0];
        P += v[c][1];
        M += v[c][2];
        Q += v[c][3];
        R += v[c][4];
    }

    double cd = (double)A * (double)P
              - 2.0 * (double)M * (double)Q
              + (double)BB * (double)R;

    // wave (64-lane) shuffle reduce, then LDS across the 8 waves
    for (int off = 32; off > 0; off >>= 1)
        cd += __shfl_down(cd, off, 64);

    __shared__ double sred[DD / 64];
    const int wid = threadIdx.x >> 6;
    const int lane = threadIdx.x & 63;
    if (lane == 0) sred[wid] = cd;
    __syncthreads();

    if (threadIdx.x == 0) {
        double full = 0.0;
#pragma unroll
        for (int w = 0; w < DD / 64; ++w) full += sred[w];
        const double result = (full - (double)DD * (double)BB * (double)BB)
                              / (2.0 * (double)BB);
        out[0] = (float)result;
    }
}

extern "C" void kernel_launch(void* const* d_in, const int* in_sizes, int n_in,
                              void* d_out, int out_size, void* d_ws, size_t ws_size,
                              hipStream_t stream) {
    const float* mu = (const float*)d_in[0];
    const float* lv = (const float*)d_in[1];
    float* out = (float*)d_out;
    float* ws = (float*)d_ws;

    udl_phase1<<<NCHUNK, DD, 0, stream>>>(mu, lv, ws);
    udl_phase2<<<1, DD, 0, stream>>>(ws, out);
}